// Round 7
// baseline (26.872 us; speedup 1.0000x reference)
//
#include <hip/hip_runtime.h>
#include <math.h>

namespace {
constexpr int NB   = 256;
constexpr int NA   = 64;
constexpr int EMBD = 64;
constexpr int HIDD = 128;
constexpr int OUTD = 512;
constexpr int FPS  = 136;   // short-stride for bf16 LDS tiles (272 B rows: conflict-free frag reads)

typedef __attribute__((ext_vector_type(8))) short bfrag8;   // 8 bf16 = 4 VGPRs
typedef __attribute__((ext_vector_type(4))) float floatx4;  // MFMA accumulator

__device__ __forceinline__ unsigned short bf16_rne(float f) {
    unsigned u = __float_as_uint(f);
    u += 0x7fffu + ((u >> 16) & 1u);
    return (unsigned short)(u >> 16);
}

// branch-free exact-GELU: erf via Abramowitz-Stegun 7.1.26 (|err| <= 1.5e-7)
__device__ __forceinline__ float gelu_fast(float x) {
    const float ax = fabsf(x) * 0.7071067811865475f;
    const float t  = __builtin_amdgcn_rcpf(fmaf(0.3275911f, ax, 1.0f));
    float p = fmaf(1.061405429f, t, -1.453152027f);
    p = fmaf(p, t, 1.421413741f);
    p = fmaf(p, t, -0.284496736f);
    p = fmaf(p, t, 0.254829592f);
    p = p * t;
    const float e = __builtin_amdgcn_exp2f(-1.4426950408889634f * ax * ax);
    const float erfx = copysignf(fmaf(-p, e, 1.0f), x);
    const float hx   = 0.5f * x;
    return fmaf(hx, erfx, hx);
}

// W1-fragment LDS layout (shorts): hi at (fg*64+ls)*8 + r, lo at +16384,
// fg = ks*8 + tile;  element = W1[ks*32+(ls>>4)*8+r][tile*16+(ls&15)]

__global__ __launch_bounds__(1024, 1)
void mlip_fused(const int*   __restrict__ atomic_nums,
                const float* __restrict__ coords,
                const float* __restrict__ embed_table,
                const float* __restrict__ W1, const float* __restrict__ b1,
                const float* __restrict__ W2, const float* __restrict__ b2,
                const float* __restrict__ Wo, const float* __restrict__ bo,
                const float* __restrict__ centers,
                float*       __restrict__ out)
{
    const int b    = blockIdx.x;
    const int tid  = threadIdx.x;
    const int lane = tid & 63;
    const int wid  = tid >> 6;          // 16 waves

    __shared__ float s_dist[NA * NA];                  // 16 KB; reused as GEMV partial buf
    __shared__ short s_w[2 * 16384];                   // 64 KB: W1 frags hi|lo
    __shared__ short s_fhi[NA][FPS], s_flo[NA][FPS];   // feat bf16 hi/lo (34 KB)
    __shared__ float s_mol[4][HIDD];                   // per-wm column sums of gelu out
    __shared__ float s_molv[HIDD];

    // ---- tiling ids
    const int wm      = wid & 3, wn = wid >> 2;
    const int lrow    = lane & 15, g4 = lane >> 4;
    const int arow    = (wm << 4) + lrow;
    const int colbase = (wn << 5) + lrow;

    // ---- GEMV ids + tail ids
    const int gcol = tid & 127, kc = tid >> 7;         // kc in [0,8)
    const int colT = tid >> 1, kh = tid & 1;

    // ---- small preloads
    const float bo_r = bo[colT];
    const float b1a  = b1[colbase];
    const float b1b  = b1[colbase + 16];
    const float b2r  = b2[gcol];
    const float c    = centers[lane];

    // ---- issue W1 loads early (indices recomputed inline; no persistent index regs)
    float w1v[16];
#pragma unroll
    for (int a = 0; a < 2; ++a) {
        const int slot = (a << 10) + tid;
        const int fg = slot >> 6, ls = slot & 63;
        const int k0 = ((fg >> 3) << 5) + ((ls >> 4) << 3);
        const int n  = ((fg & 7) << 4) + (ls & 15);
        const float* src = W1 + (size_t)k0 * HIDD + n;
#pragma unroll
        for (int r = 0; r < 8; ++r) w1v[a * 8 + r] = src[(size_t)r * HIDD];
    }

    // ---- coords + embedding
    const float* cbase = coords + (size_t)b * NA * 3;
    const float cx = cbase[lane * 3 + 0];
    const float cy = cbase[lane * 3 + 1];
    const float cz = cbase[lane * 3 + 2];
    {
        const int i = tid >> 4, e4 = (tid & 15) << 2;
        const int z = atomic_nums[b * NA + i];
        const float4 ev = *(const float4*)(embed_table + (size_t)z * EMBD + e4);
        short4 h4, l4;
        const float v[4] = {ev.x, ev.y, ev.z, ev.w};
        short* hp = (short*)&h4; short* lp = (short*)&l4;
#pragma unroll
        for (int q = 0; q < 4; ++q) {
            const unsigned short h = bf16_rne(v[q]);
            hp[q] = (short)h;
            lp[q] = (short)bf16_rne(v[q] - __uint_as_float((unsigned)h << 16));
        }
        *(short4*)&s_fhi[i][e4] = h4;
        *(short4*)&s_flo[i][e4] = l4;
    }

    // ---- dist rows this wave will itself consume (within-wave dep only)
#pragma unroll
    for (int it = 0; it < 4; ++it) {
        const int i = wid + (it << 4);
        const float xi = __shfl(cx, i, 64);
        const float yi = __shfl(cy, i, 64);
        const float zi = __shfl(cz, i, 64);
        const float dx = xi - cx, dy = yi - cy, dz = zi - cz;
        const float sq = dx * dx + dy * dy + dz * dz;
        s_dist[(i << 6) + lane] = sq > 0.0f ? sqrtf(sq) : 0.0f;
    }

    // ---- convert W1 -> s_w (hi/lo, b128 stores); w1v dies here
#pragma unroll
    for (int a = 0; a < 2; ++a) {
        unsigned Hu[4], Lu[4];
#pragma unroll
        for (int p = 0; p < 4; ++p) {
            const float x = w1v[a * 8 + 2 * p], y = w1v[a * 8 + 2 * p + 1];
            unsigned h;
            asm("v_cvt_pk_bf16_f32 %0, %1, %2" : "=v"(h) : "v"(x), "v"(y));
            const float hx = __uint_as_float(h << 16);
            const float hy = __uint_as_float(h & 0xffff0000u);
            unsigned l;
            asm("v_cvt_pk_bf16_f32 %0, %1, %2" : "=v"(l) : "v"(x - hx), "v"(y - hy));
            Hu[p] = h; Lu[p] = l;
        }
        const int slot = (a << 10) + tid;
        const int base = ((slot >> 6) << 9) + (slot & 63) * 8;
        *(uint4*)&s_w[base]         = make_uint4(Hu[0], Hu[1], Hu[2], Hu[3]);
        *(uint4*)&s_w[16384 + base] = make_uint4(Lu[0], Lu[1], Lu[2], Lu[3]);
    }

    // ---- gaussian smear, mean over j -> s_f[:, 64:128]
    {
        const float K2  = -2.8853900817779268f;   // -2*log2(e)
        const float nu2 = -2.0f * K2 * c;
        const float vc  = K2 * c * c;
#pragma unroll
        for (int it = 0; it < 4; ++it) {
            const int i = wid + (it << 4);
            const float* drow = &s_dist[i << 6];
            float a0 = 0.f, a1 = 0.f, a2 = 0.f, a3 = 0.f;
#pragma unroll
            for (int j4 = 0; j4 < NA; j4 += 4) {
                const float4 d4 = *(const float4*)(drow + j4);
                a0 += __builtin_amdgcn_exp2f(fmaf(d4.x, fmaf(K2, d4.x, nu2), vc));
                a1 += __builtin_amdgcn_exp2f(fmaf(d4.y, fmaf(K2, d4.y, nu2), vc));
                a2 += __builtin_amdgcn_exp2f(fmaf(d4.z, fmaf(K2, d4.z, nu2), vc));
                a3 += __builtin_amdgcn_exp2f(fmaf(d4.w, fmaf(K2, d4.w, nu2), vc));
            }
            const float acc = ((a0 + a1) + (a2 + a3)) * (1.0f / 64.0f);
            const unsigned short h = bf16_rne(acc);
            s_fhi[i][EMBD + lane] = (short)h;
            s_flo[i][EMBD + lane] =
                (short)bf16_rne(acc - __uint_as_float((unsigned)h << 16));
        }
    }
    __syncthreads();                                   // barrier 1: feat + W1 frags ready

    // ---- stage 3: G = gelu(feat @ W1 + b1); column sums of G folded in-register
    float wo_a[32];
    float w2r[16];
    {
        floatx4 acc0 = {0,0,0,0}, acc1 = {0,0,0,0};
#pragma unroll
        for (int ks = 0; ks < 4; ++ks) {
            const int k0 = (ks << 5) + (g4 << 3);
            const bfrag8 ahi = *(const bfrag8*)&s_fhi[arow][k0];
            const bfrag8 alo = *(const bfrag8*)&s_flo[arow][k0];
#pragma unroll
            for (int nt = 0; nt < 2; ++nt) {
                const int base = ((((ks << 3) + (wn << 1) + nt) << 6) + lane) << 3;
                const bfrag8 bhi = *(const bfrag8*)&s_w[base];
                const bfrag8 blo = *(const bfrag8*)&s_w[16384 + base];
                floatx4 a = nt ? acc1 : acc0;
                a = __builtin_amdgcn_mfma_f32_16x16x32_bf16(ahi, bhi, a, 0, 0, 0);
                a = __builtin_amdgcn_mfma_f32_16x16x32_bf16(ahi, blo, a, 0, 0, 0);
                a = __builtin_amdgcn_mfma_f32_16x16x32_bf16(alo, bhi, a, 0, 0, 0);
                if (nt) acc1 = a; else acc0 = a;
            }
        }

        // issue first Wo half + W2 GEMV rows now (hidden under gelu/reduce/barrier)
        {
            const float* wop = Wo + ((size_t)(kh << 6)) * OUTD + colT;
#pragma unroll
            for (int k = 0; k < 32; ++k) wo_a[k] = wop[(size_t)k * OUTD];
            const float* src = W2 + (size_t)(kc << 4) * HIDD + gcol;
#pragma unroll
            for (int q = 0; q < 16; ++q) w2r[q] = src[(size_t)q * HIDD];
        }

        // gelu + column reduce: rows g4*4+r summed in-lane, then across g4 groups
#pragma unroll
        for (int nt = 0; nt < 2; ++nt) {
            const float bb = nt ? b1b : b1a;
            const floatx4 a = nt ? acc1 : acc0;
            float s = gelu_fast(a[0] + bb) + gelu_fast(a[1] + bb)
                    + gelu_fast(a[2] + bb) + gelu_fast(a[3] + bb);
            s += __shfl_xor(s, 16, 64);
            s += __shfl_xor(s, 32, 64);
            if (lane < 16) s_mol[wm][colbase + (nt << 4)] = s;   // col-sum of 16 rows
        }
    }
    __syncthreads();                                   // barrier 2: s_mol ready

    // ---- GEMV: mol_raw[col] = sum_k (sum_wm s_mol[wm][k]) * W2[k][col]
    float wo_b[32];
    {
        float acc = 0.0f;
        const int kb = kc << 4;
#pragma unroll
        for (int q = 0; q < 16; ++q) {
            const int k = kb + q;
            const float hk = (s_mol[0][k] + s_mol[1][k])
                           + (s_mol[2][k] + s_mol[3][k]);   // wave-uniform broadcasts
            acc = fmaf(hk, w2r[q], acc);
        }
        s_dist[(kc << 7) + gcol] = acc;                // s_dist reused as partial buf

        // issue second Wo half (hidden under barrier 3 + reduce + barrier 4)
        const float* wop = Wo + ((size_t)((kh << 6) + 32)) * OUTD + colT;
#pragma unroll
        for (int k = 0; k < 32; ++k) wo_b[k] = wop[(size_t)k * OUTD];
    }
    __syncthreads();                                   // barrier 3: partials ready

    // ---- mol = colsum/64 + b2
    if (tid < HIDD) {
        float m = 0.0f;
#pragma unroll
        for (int p = 0; p < 8; ++p) m += s_dist[(p << 7) + tid];
        s_molv[tid] = m * (1.0f / 64.0f) + b2r;
    }
    __syncthreads();                                   // barrier 4: molv ready

    // ---- tail: out = mol @ Wo + bo; lane-pair K-split, shfl combine
    {
        const float* mp = &s_molv[kh << 6];
        float a = 0.0f;
#pragma unroll
        for (int k = 0; k < 32; ++k) a = fmaf(mp[k], wo_a[k], a);
#pragma unroll
        for (int k = 0; k < 32; ++k) a = fmaf(mp[32 + k], wo_b[k], a);
        a += __shfl_xor(a, 1, 64);
        if (kh == 0)
            out[(size_t)b * OUTD + colT] = a + bo_r;
    }
}
} // namespace

extern "C" void kernel_launch(void* const* d_in, const int* in_sizes, int n_in,
                              void* d_out, int out_size, void* d_ws, size_t ws_size,
                              hipStream_t stream) {
    const int*   atomic_nums = (const int*)  d_in[0];
    const float* coords      = (const float*)d_in[1];
    const float* embed_table = (const float*)d_in[2];
    const float* W1          = (const float*)d_in[3];
    const float* b1          = (const float*)d_in[4];
    const float* W2          = (const float*)d_in[5];
    const float* b2          = (const float*)d_in[6];
    const float* Wo          = (const float*)d_in[7];
    const float* bo          = (const float*)d_in[8];
    const float* centers     = (const float*)d_in[9];
    float*       out         = (float*)d_out;

    mlip_fused<<<NB, 1024, 0, stream>>>(atomic_nums, coords, embed_table,
                                        W1, b1, W2, b2, Wo, bo, centers, out);
}

// Round 8
// 25.682 us; speedup vs baseline: 1.0463x; 1.0463x over previous
//
#include <hip/hip_runtime.h>
#include <math.h>

namespace {
constexpr int NB   = 256;
constexpr int NA   = 64;
constexpr int EMBD = 64;
constexpr int HIDD = 128;
constexpr int OUTD = 512;
constexpr int FPS  = 136;  // short-stride for bf16 LDS tiles (272 B rows: conflict-free frag reads)
constexpr int DSTR = 68;   // padded float-stride for s_dist (row-group reads -> 2-way banks)

typedef __attribute__((ext_vector_type(8))) short bfrag8;   // 8 bf16 = 4 VGPRs
typedef __attribute__((ext_vector_type(4))) float floatx4;  // MFMA accumulator

__device__ __forceinline__ unsigned short bf16_rne(float f) {
    unsigned u = __float_as_uint(f);
    u += 0x7fffu + ((u >> 16) & 1u);
    return (unsigned short)(u >> 16);
}

// branch-free exact-GELU: erf via Abramowitz-Stegun 7.1.26 (|err| <= 1.5e-7)
__device__ __forceinline__ float gelu_fast(float x) {
    const float ax = fabsf(x) * 0.7071067811865475f;
    const float t  = __builtin_amdgcn_rcpf(fmaf(0.3275911f, ax, 1.0f));
    float p = fmaf(1.061405429f, t, -1.453152027f);
    p = fmaf(p, t, 1.421413741f);
    p = fmaf(p, t, -0.284496736f);
    p = fmaf(p, t, 0.254829592f);
    p = p * t;
    const float e = __builtin_amdgcn_exp2f(-1.4426950408889634f * ax * ax);
    const float erfx = copysignf(fmaf(-p, e, 1.0f), x);
    const float hx   = 0.5f * x;
    return fmaf(hx, erfx, hx);
}

// W1-fragment LDS layout (shorts): hi at (fg*64+ls)*8 + r, lo at +16384,
// fg = ks*8 + tile;  element = W1[ks*32+(ls>>4)*8+r][tile*16+(ls&15)]

__global__ __launch_bounds__(1024, 1)
void mlip_fused(const int*   __restrict__ atomic_nums,
                const float* __restrict__ coords,
                const float* __restrict__ embed_table,
                const float* __restrict__ W1, const float* __restrict__ b1,
                const float* __restrict__ W2, const float* __restrict__ b2,
                const float* __restrict__ Wo, const float* __restrict__ bo,
                const float* __restrict__ centers,
                float*       __restrict__ out)
{
    const int b    = blockIdx.x;
    const int tid  = threadIdx.x;
    const int lane = tid & 63;
    const int wid  = tid >> 6;          // 16 waves

    __shared__ float s_dist[NA * DSTR];                // 17 KB; reused as GEMV partial buf
    __shared__ short s_w[2 * 16384];                   // 64 KB: W1 frags hi|lo
    __shared__ short s_fhi[NA][FPS], s_flo[NA][FPS];   // feat bf16 hi/lo (34 KB)
    __shared__ float s_mol[4][HIDD];                   // per-wm column sums of gelu out
    __shared__ float s_molv[HIDD];

    // ---- tiling ids
    const int wm      = wid & 3, wn = wid >> 2;
    const int lrow    = lane & 15, g4 = lane >> 4;
    const int arow    = (wm << 4) + lrow;
    const int colbase = (wn << 5) + lrow;

    // ---- GEMV ids + tail ids
    const int gcol = tid & 127, kc = tid >> 7;         // kc in [0,8)
    const int colT = tid >> 1, kh = tid & 1;

    // ---- gauss recurrence ids: thread = (row, g-chunk, j-quarter)
    const int grow = tid >> 4;          // row i in [0,64)
    const int gch  = (tid >> 2) & 3;    // 16-center chunk
    const int jq   = tid & 3;           // 16-j quarter

    // ---- small preloads
    const float bo_r = bo[colT];
    const float b1a  = b1[colbase];
    const float b1b  = b1[colbase + 16];
    const float b2r  = b2[gcol];
    const float c0   = centers[gch << 4];   // chunk base center (input-exact)

    // ---- issue W1 loads early (indices recomputed inline)
    float w1v[16];
#pragma unroll
    for (int a = 0; a < 2; ++a) {
        const int slot = (a << 10) + tid;
        const int fg = slot >> 6, ls = slot & 63;
        const int k0 = ((fg >> 3) << 5) + ((ls >> 4) << 3);
        const int n  = ((fg & 7) << 4) + (ls & 15);
        const float* src = W1 + (size_t)k0 * HIDD + n;
#pragma unroll
        for (int r = 0; r < 8; ++r) w1v[a * 8 + r] = src[(size_t)r * HIDD];
    }

    // ---- coords + embedding
    const float* cbase = coords + (size_t)b * NA * 3;
    const float cx = cbase[lane * 3 + 0];
    const float cy = cbase[lane * 3 + 1];
    const float cz = cbase[lane * 3 + 2];
    {
        const int i = tid >> 4, e4 = (tid & 15) << 2;
        const int z = atomic_nums[b * NA + i];
        const float4 ev = *(const float4*)(embed_table + (size_t)z * EMBD + e4);
        short4 h4, l4;
        const float v[4] = {ev.x, ev.y, ev.z, ev.w};
        short* hp = (short*)&h4; short* lp = (short*)&l4;
#pragma unroll
        for (int q = 0; q < 4; ++q) {
            const unsigned short h = bf16_rne(v[q]);
            hp[q] = (short)h;
            lp[q] = (short)bf16_rne(v[q] - __uint_as_float((unsigned)h << 16));
        }
        *(short4*)&s_fhi[i][e4] = h4;
        *(short4*)&s_flo[i][e4] = l4;
    }

    // ---- pairwise distances: wave w writes rows {w, w+16, w+32, w+48}, j = lane
#pragma unroll
    for (int it = 0; it < 4; ++it) {
        const int i = wid + (it << 4);
        const float xi = __shfl(cx, i, 64);
        const float yi = __shfl(cy, i, 64);
        const float zi = __shfl(cz, i, 64);
        const float dx = xi - cx, dy = yi - cy, dz = zi - cz;
        const float sq = dx * dx + dy * dy + dz * dz;
        s_dist[i * DSTR + lane] = sq > 0.0f ? sqrtf(sq) : 0.0f;
    }

    // ---- convert W1 -> s_w (hi/lo, b128 stores); w1v dies here
#pragma unroll
    for (int a = 0; a < 2; ++a) {
        unsigned Hu[4], Lu[4];
#pragma unroll
        for (int p = 0; p < 4; ++p) {
            const float x = w1v[a * 8 + 2 * p], y = w1v[a * 8 + 2 * p + 1];
            unsigned h;
            asm("v_cvt_pk_bf16_f32 %0, %1, %2" : "=v"(h) : "v"(x), "v"(y));
            const float hx = __uint_as_float(h << 16);
            const float hy = __uint_as_float(h & 0xffff0000u);
            unsigned l;
            asm("v_cvt_pk_bf16_f32 %0, %1, %2" : "=v"(l) : "v"(x - hx), "v"(y - hy));
            Hu[p] = h; Lu[p] = l;
        }
        const int slot = (a << 10) + tid;
        const int base = ((slot >> 6) << 9) + (slot & 63) * 8;
        *(uint4*)&s_w[base]         = make_uint4(Hu[0], Hu[1], Hu[2], Hu[3]);
        *(uint4*)&s_w[16384 + base] = make_uint4(Lu[0], Lu[1], Lu[2], Lu[3]);
    }
    __syncthreads();                                   // barrier 0: s_dist complete

    // ---- gaussian smear via geometric recurrence:
    // t_g = exp(-2(d-c_g)^2);  t_{g+1} = t_g*u;  u *= WF (const).
    // 2 exp2 per (j, 16-center chunk) instead of 16.
    {
        constexpr float L2E   = 1.4426950408889634f;
        constexpr float DELTA = 10.0f / 63.0f;
        constexpr float K2L   = -2.0f * L2E;             // exp2 coeff for x^2
        constexpr float UA    = 4.0f * DELTA * L2E;      // u-arg slope
        constexpr float UB    = -2.0f * DELTA * DELTA * L2E;
        constexpr float WF    = 0.9041312f;              // exp(-4*DELTA^2)

        float acc[16];
#pragma unroll
        for (int q = 0; q < 16; ++q) acc[q] = 0.0f;

        const float* drow = &s_dist[grow * DSTR + (jq << 4)];
#pragma unroll
        for (int j4 = 0; j4 < 4; ++j4) {
            const float4 d4 = *(const float4*)(drow + (j4 << 2));
            const float dv[4] = {d4.x, d4.y, d4.z, d4.w};
#pragma unroll
            for (int jj = 0; jj < 4; ++jj) {
                const float x = dv[jj] - c0;
                float t = __builtin_amdgcn_exp2f(K2L * x * x);
                float u = __builtin_amdgcn_exp2f(fmaf(UA, x, UB));
#pragma unroll
                for (int q = 0; q < 16; ++q) { acc[q] += t; t *= u; u *= WF; }
            }
        }
        // reduce over j-quarters (lane bits 0-1)
#pragma unroll
        for (int q = 0; q < 16; ++q) {
            acc[q] += __shfl_xor(acc[q], 1, 64);
            acc[q] += __shfl_xor(acc[q], 2, 64);
        }
        if (jq == 0) {
            // 16 consecutive g-values -> 8 packed u32 writes per array
            unsigned* hp = (unsigned*)&s_fhi[grow][EMBD + (gch << 4)];
            unsigned* lp = (unsigned*)&s_flo[grow][EMBD + (gch << 4)];
#pragma unroll
            for (int q2 = 0; q2 < 8; ++q2) {
                const float v0 = acc[2 * q2]     * (1.0f / 64.0f);
                const float v1 = acc[2 * q2 + 1] * (1.0f / 64.0f);
                const unsigned h0 = bf16_rne(v0), h1 = bf16_rne(v1);
                const unsigned l0 = bf16_rne(v0 - __uint_as_float(h0 << 16));
                const unsigned l1 = bf16_rne(v1 - __uint_as_float(h1 << 16));
                hp[q2] = h0 | (h1 << 16);
                lp[q2] = l0 | (l1 << 16);
            }
        }
    }
    __syncthreads();                                   // barrier 1: feat + W1 frags ready

    // ---- stage 3: G = gelu(feat @ W1 + b1); column sums of G folded in-register
    float wo_a[32];
    float w2r[16];
    {
        floatx4 acc0 = {0,0,0,0}, acc1 = {0,0,0,0};
#pragma unroll
        for (int ks = 0; ks < 4; ++ks) {
            const int k0 = (ks << 5) + (g4 << 3);
            const bfrag8 ahi = *(const bfrag8*)&s_fhi[arow][k0];
            const bfrag8 alo = *(const bfrag8*)&s_flo[arow][k0];
#pragma unroll
            for (int nt = 0; nt < 2; ++nt) {
                const int base = ((((ks << 3) + (wn << 1) + nt) << 6) + lane) << 3;
                const bfrag8 bhi = *(const bfrag8*)&s_w[base];
                const bfrag8 blo = *(const bfrag8*)&s_w[16384 + base];
                floatx4 a = nt ? acc1 : acc0;
                a = __builtin_amdgcn_mfma_f32_16x16x32_bf16(ahi, bhi, a, 0, 0, 0);
                a = __builtin_amdgcn_mfma_f32_16x16x32_bf16(ahi, blo, a, 0, 0, 0);
                a = __builtin_amdgcn_mfma_f32_16x16x32_bf16(alo, bhi, a, 0, 0, 0);
                if (nt) acc1 = a; else acc0 = a;
            }
        }

        // issue first Wo half + W2 GEMV rows now (hidden under gelu/reduce/barrier)
        {
            const float* wop = Wo + ((size_t)(kh << 6)) * OUTD + colT;
#pragma unroll
            for (int k = 0; k < 32; ++k) wo_a[k] = wop[(size_t)k * OUTD];
            const float* src = W2 + (size_t)(kc << 4) * HIDD + gcol;
#pragma unroll
            for (int q = 0; q < 16; ++q) w2r[q] = src[(size_t)q * HIDD];
        }

        // gelu + column reduce: rows g4*4+r summed in-lane, then across g4 groups
#pragma unroll
        for (int nt = 0; nt < 2; ++nt) {
            const float bb = nt ? b1b : b1a;
            const floatx4 a = nt ? acc1 : acc0;
            float s = gelu_fast(a[0] + bb) + gelu_fast(a[1] + bb)
                    + gelu_fast(a[2] + bb) + gelu_fast(a[3] + bb);
            s += __shfl_xor(s, 16, 64);
            s += __shfl_xor(s, 32, 64);
            if (lane < 16) s_mol[wm][colbase + (nt << 4)] = s;   // col-sum of 16 rows
        }
    }
    __syncthreads();                                   // barrier 2: s_mol ready

    // ---- GEMV: mol_raw[col] = sum_k (sum_wm s_mol[wm][k]) * W2[k][col]
    float wo_b[32];
    {
        float acc = 0.0f;
        const int kb = kc << 4;
#pragma unroll
        for (int q = 0; q < 16; ++q) {
            const int k = kb + q;
            const float hk = (s_mol[0][k] + s_mol[1][k])
                           + (s_mol[2][k] + s_mol[3][k]);   // wave-uniform broadcasts
            acc = fmaf(hk, w2r[q], acc);
        }
        s_dist[(kc << 7) + gcol] = acc;                // s_dist reused as partial buf

        // issue second Wo half (hidden under barrier 3 + reduce + barrier 4)
        const float* wop = Wo + ((size_t)((kh << 6) + 32)) * OUTD + colT;
#pragma unroll
        for (int k = 0; k < 32; ++k) wo_b[k] = wop[(size_t)k * OUTD];
    }
    __syncthreads();                                   // barrier 3: partials ready

    // ---- mol = colsum/64 + b2
    if (tid < HIDD) {
        float m = 0.0f;
#pragma unroll
        for (int p = 0; p < 8; ++p) m += s_dist[(p << 7) + tid];
        s_molv[tid] = m * (1.0f / 64.0f) + b2r;
    }
    __syncthreads();                                   // barrier 4: molv ready

    // ---- tail: out = mol @ Wo + bo; lane-pair K-split, shfl combine
    {
        const float* mp = &s_molv[kh << 6];
        float a = 0.0f;
#pragma unroll
        for (int k = 0; k < 32; ++k) a = fmaf(mp[k], wo_a[k], a);
#pragma unroll
        for (int k = 0; k < 32; ++k) a = fmaf(mp[32 + k], wo_b[k], a);
        a += __shfl_xor(a, 1, 64);
        if (kh == 0)
            out[(size_t)b * OUTD + colT] = a + bo_r;
    }
}
} // namespace

extern "C" void kernel_launch(void* const* d_in, const int* in_sizes, int n_in,
                              void* d_out, int out_size, void* d_ws, size_t ws_size,
                              hipStream_t stream) {
    const int*   atomic_nums = (const int*)  d_in[0];
    const float* coords      = (const float*)d_in[1];
    const float* embed_table = (const float*)d_in[2];
    const float* W1          = (const float*)d_in[3];
    const float* b1          = (const float*)d_in[4];
    const float* W2          = (const float*)d_in[5];
    const float* b2          = (const float*)d_in[6];
    const float* Wo          = (const float*)d_in[7];
    const float* bo          = (const float*)d_in[8];
    const float* centers     = (const float*)d_in[9];
    float*       out         = (float*)d_out;

    mlip_fused<<<NB, 1024, 0, stream>>>(atomic_nums, coords, embed_table,
                                        W1, b1, W2, b2, Wo, bo, centers, out);
}